// Round 11
// baseline (201.293 us; speedup 1.0000x reference)
//
#include <hip/hip_runtime.h>
#include <type_traits>

namespace {
constexpr int HH = 512;
constexpr int WW = 512;
constexpr int KS = 11;
constexpr int PADR = 5;
constexpr int TH = 32;                 // tile rows per block
constexpr int TW = 64;                 // tile cols per block
constexpr int SLAB = 16;               // rows per slab
constexpr int HC = TW + 2 * PADR;      // 74 columns incl. horizontal halo
constexpr int LPA = 148;               // interleaved pair rows: 74 cols x 2
constexpr int LPC = 76;                // scalar sxy rows
constexpr int NTHREADS = 512;          // 8 waves per block
constexpr float SSIM_C1 = 1.0e-4f;     // (0.01*1.0)^2
constexpr float SSIM_C2 = 9.0e-4f;     // (0.03*1.0)^2
}

typedef float v2f __attribute__((ext_vector_type(2)));
typedef float v4f __attribute__((ext_vector_type(4)));
#define LOWP(v)  __builtin_shufflevector(v, v, 0, 1)
#define HIGHP(v) __builtin_shufflevector(v, v, 2, 3)

// R10 kernel (verified: 102us steady, occ 73%, VALU 57%, FETCH 104MB) with
// ONE change: phase 2 now uses ALL 512 threads at 2 outputs each (R10 idled
// threads >=256 through ~40% of the kernel; the per-thread phase-2 chain set
// the inter-barrier critical path). Mapping: half=t>>8 (wave-uniform),
// row=(t>>4)&15, m=t&15, oc=32*half+2*m. Window = 12 pairs -> float base
// 64h+4m (16B-aligned) -> exactly 6 v4f reads, max index 147 < LPA=148
// (layout untouched); pC = 6 aligned v2f; stores 16-lane-contiguous 128B
// float2. Per-thread phase-2: 19 reads+132 FMA -> 16 reads+66 FMA. Phase 1,
// tile, slab, LDS layout byte-identical to R10.
__global__ __launch_bounds__(NTHREADS, 8) void ssim_fused(
    const float* __restrict__ x, const float* __restrict__ y,
    const float* __restrict__ kern, float* __restrict__ out)
{
    __shared__ __align__(16) float pA[SLAB][LPA];   // (sx,sy) interleaved
    __shared__ __align__(16) float pB_[SLAB][LPA];  // (sxx,syy) interleaved
    __shared__ __align__(16) float pC_[SLAB][LPC];  // sxy scalar
    // total 23808 B; 4 blocks/CU (wave-capped) = 95KB of 160KB LDS

    constexpr int tiles_w = WW / TW;         // 8
    constexpr int tiles_h = HH / TH;         // 16
    constexpr int tpp = tiles_w * tiles_h;   // 128 tiles per plane

    const int bid = blockIdx.x;
    const int plane = bid / tpp;
    const int trem = bid - plane * tpp;
    const int tr_idx = trem / tiles_w;
    const int tile_r = tr_idx * TH;
    const int tile_c = (trem - tr_idx * tiles_w) * TW;

    const float* __restrict__ xp = x + (size_t)plane * (HH * WW);
    const float* __restrict__ yp = y + (size_t)plane * (HH * WW);
    float* __restrict__ op = out + (size_t)plane * (HH * WW);

    // 1D gaussian weights (exact for outer products), broadcast pairs.
    // Kernel is symmetric: taps 6..10 mirror 4..0 -> 6 unique weights.
    v2f pw[6];
    {
        const float inv = rsqrtf(kern[5 * KS + 5]);
#pragma unroll
        for (int i = 0; i < 6; ++i) {
            const float w = kern[5 * KS + i] * inv;
            v2f tmp = {w, w};
            pw[i] = tmp;
        }
    }

    const int t = threadIdx.x;
    const bool interior = (tile_r >= PADR) && (tile_r + TH + PADR <= HH) &&
                          (tile_c >= PADR) && (tile_c + TW + PADR <= WW);

    // phase-2 mapping: 512 threads x 2 outputs = 16 rows x 64 cols
    const int p2_h = t >> 8;           // 0..1 (wave-uniform col half)
    const int p2_r = (t >> 4) & 15;    // 0..15
    const int p2_m = t & 15;           // 0..15
    const int p2_oc = 32 * p2_h + 2 * p2_m;   // local output col, 0..62

    auto run_slab = [&](int s0, auto intr_tag) {
        constexpr bool INTR = decltype(intr_tag)::value;
        // ---- phase 1: vertical 11-tap blur into LDS, row pairs, packed.
        // 8 row-pairs x 74 cols = 592 positions over 512 threads (1.16).
        for (int i = t; i < (SLAB / 2) * HC; i += NTHREADS) {
            const int r2 = i / HC;
            const int c = i - r2 * HC;
            const int gr = tile_r + s0 + 2 * r2;   // first output row of pair
            const int gc = tile_c + c - PADR;      // input col (maybe OOB)
            v2f uvA = {0.f, 0.f}, qqA = {0.f, 0.f};
            v2f uvB = {0.f, 0.f}, qqB = {0.f, 0.f};
            float xyA = 0.f, xyB = 0.f;
            const float* xq = xp + (gr - PADR) * WW + gc;
            const float* yq = yp + (gr - PADR) * WW + gc;
#pragma unroll
            for (int k = 0; k < KS + 1; ++k) {       // 12 input rows
                float xv, yv;
                if (INTR) {
                    xv = xq[k * WW];
                    yv = yq[k * WW];
                } else {
                    const int rr = gr - PADR + k;
                    const bool ok = (gc >= 0) & (gc < WW) & (rr >= 0) & (rr < HH);
                    xv = 0.f; yv = 0.f;
                    if (ok) {
                        xv = xp[rr * WW + gc];
                        yv = yp[rr * WW + gc];
                    }
                }
                v2f v2 = {xv, yv};
                const v2f q2 = v2 * v2;              // v_pk_mul_f32
                const float xy = xv * yv;
                if (k < KS) {                        // row A taps 0..10
                    const v2f w = pw[k < 6 ? k : 10 - k];
                    uvA += w * v2;                   // v_pk_fma_f32
                    qqA += w * q2;
                    xyA += w.x * xy;
                }
                if (k >= 1) {                        // row B taps 0..10
                    const v2f w = pw[(k - 1) < 6 ? (k - 1) : 11 - k];
                    uvB += w * v2;
                    qqB += w * q2;
                    xyB += w.x * xy;
                }
            }
            const int rA = 2 * r2, rB = 2 * r2 + 1;
            *(v2f*)&pA[rA][2 * c] = uvA;   *(v2f*)&pA[rB][2 * c] = uvB;
            *(v2f*)&pB_[rA][2 * c] = qqA;  *(v2f*)&pB_[rB][2 * c] = qqB;
            pC_[rA][c] = xyA;              pC_[rB][c] = xyB;
        }
        __syncthreads();

        // ---- phase 2: horizontal 11-tap blur (packed) + SSIM, 2 outputs
        // per thread, all 512 threads. Window = 12 pairs (P0..P11) at LDS
        // cols oc..oc+11; float base 2*oc = 64h+4m is 16B-aligned -> 6 v4f.
#define PCONV2(R0, R1, b0, b1, b2, b3, b4, b5)                                  \
    R0 += pw[0]*LOWP(b0); R0 += pw[1]*HIGHP(b0); R0 += pw[2]*LOWP(b1);          \
    R0 += pw[3]*HIGHP(b1); R0 += pw[4]*LOWP(b2); R0 += pw[5]*HIGHP(b2);         \
    R0 += pw[4]*LOWP(b3); R0 += pw[3]*HIGHP(b3); R0 += pw[2]*LOWP(b4);          \
    R0 += pw[1]*HIGHP(b4); R0 += pw[0]*LOWP(b5);                                \
    R1 += pw[0]*HIGHP(b0); R1 += pw[1]*LOWP(b1); R1 += pw[2]*HIGHP(b1);         \
    R1 += pw[3]*LOWP(b2); R1 += pw[4]*HIGHP(b2); R1 += pw[5]*LOWP(b3);          \
    R1 += pw[4]*HIGHP(b3); R1 += pw[3]*LOWP(b4); R1 += pw[2]*HIGHP(b4);         \
    R1 += pw[1]*LOWP(b5); R1 += pw[0]*HIGHP(b5);

#define SCONV(R, S0, S1, S2, S3, S4, S5, S6, S7, S8, S9, S10)                   \
    R += pw[0].x*S0; R += pw[1].x*S1; R += pw[2].x*S2; R += pw[3].x*S3;         \
    R += pw[4].x*S4; R += pw[5].x*S5; R += pw[4].x*S6; R += pw[3].x*S7;         \
    R += pw[2].x*S8; R += pw[1].x*S9; R += pw[0].x*S10;

        v2f rUV0 = {0.f, 0.f}, rUV1 = {0.f, 0.f};
        {
            const float* rowA = &pA[p2_r][2 * p2_oc];
            const v4f b0 = *(const v4f*)(rowA + 0);
            const v4f b1 = *(const v4f*)(rowA + 4);
            const v4f b2 = *(const v4f*)(rowA + 8);
            const v4f b3 = *(const v4f*)(rowA + 12);
            const v4f b4 = *(const v4f*)(rowA + 16);
            const v4f b5 = *(const v4f*)(rowA + 20);
            PCONV2(rUV0, rUV1, b0, b1, b2, b3, b4, b5)
        }
        v2f rQQ0 = {0.f, 0.f}, rQQ1 = {0.f, 0.f};
        {
            const float* rowB = &pB_[p2_r][2 * p2_oc];
            const v4f b0 = *(const v4f*)(rowB + 0);
            const v4f b1 = *(const v4f*)(rowB + 4);
            const v4f b2 = *(const v4f*)(rowB + 8);
            const v4f b3 = *(const v4f*)(rowB + 12);
            const v4f b4 = *(const v4f*)(rowB + 16);
            const v4f b5 = *(const v4f*)(rowB + 20);
            PCONV2(rQQ0, rQQ1, b0, b1, b2, b3, b4, b5)
        }
        float rC0 = 0.f, rC1 = 0.f;
        {
            const float* rowC = &pC_[p2_r][p2_oc];
            const v2f c0 = *(const v2f*)(rowC + 0);
            const v2f c1 = *(const v2f*)(rowC + 2);
            const v2f c2 = *(const v2f*)(rowC + 4);
            const v2f c3 = *(const v2f*)(rowC + 6);
            const v2f c4 = *(const v2f*)(rowC + 8);
            const v2f c5 = *(const v2f*)(rowC + 10);
            const float e0 = c0.x, e1 = c0.y, e2 = c1.x, e3 = c1.y;
            const float e4 = c2.x, e5 = c2.y, e6 = c3.x, e7 = c3.y;
            const float e8 = c4.x, e9 = c4.y, e10 = c5.x, e11 = c5.y;
            SCONV(rC0, e0, e1, e2, e3, e4, e5, e6, e7, e8, e9, e10)
            SCONV(rC1, e1, e2, e3, e4, e5, e6, e7, e8, e9, e10, e11)
        }

        v2f o2;
#pragma unroll
        for (int j = 0; j < 2; ++j) {
            const v2f uvj = (j == 0) ? rUV0 : rUV1;
            const v2f qqj = (j == 0) ? rQQ0 : rQQ1;
            const float uxy = (j == 0) ? rC0 : rC1;
            const float ux = uvj.x, uy = uvj.y;
            const float uxx = qqj.x, uyy = qqj.y;
            const float vx  = uxx - ux * ux;
            const float vy  = uyy - uy * uy;
            const float vxy = uxy - ux * uy;
            const float a1s = 2.f * ux * uy + SSIM_C1;
            const float a2s = 2.f * vxy + SSIM_C2;
            const float b1s = ux * ux + uy * uy + SSIM_C1;
            const float b2s = vx + vy + SSIM_C2;
            o2[j] = (a1s * a2s) * __builtin_amdgcn_rcpf(b1s * b2s);
        }
        *(v2f*)(op + (size_t)(tile_r + s0 + p2_r) * WW + (tile_c + p2_oc)) = o2;
        __syncthreads();   // LDS reused by next slab
#undef PCONV2
#undef SCONV
    };

    if (interior) {
        run_slab(0,    std::true_type{});
        run_slab(SLAB, std::true_type{});
    } else {
        run_slab(0,    std::false_type{});
        run_slab(SLAB, std::false_type{});
    }
}

extern "C" void kernel_launch(void* const* d_in, const int* in_sizes, int n_in,
                              void* d_out, int out_size, void* d_ws, size_t ws_size,
                              hipStream_t stream) {
    const float* x    = (const float*)d_in[0];
    const float* y    = (const float*)d_in[1];
    const float* kern = (const float*)d_in[2];
    float* out = (float*)d_out;

    const int nplanes = in_sizes[0] / (HH * WW);            // 48
    const int nblocks = nplanes * (HH / TH) * (WW / TW);    // 6144

    ssim_fused<<<dim3(nblocks), dim3(NTHREADS), 0, stream>>>(x, y, kern, out);
}